// Round 1
// baseline (183.412 us; speedup 1.0000x reference)
//
#include <hip/hip_runtime.h>
#include <math.h>

// Problem constants (from reference): S=64 subdomains, N=65536 points, W=64.
// Approach:
//   Each subnet u_s(x) is a univariate smooth function (|u''| ~ O(10)).
//   Phase 1: evaluate each subnet on a dense grid (G=7168 over [0,1]),
//            WIDTH=2304 samples per subdomain covering its PoU-relevance
//            window (|x-c_s| <= 8.5/63 = 0.135; grid half-width 1152/7168 =
//            0.161). Linear-interp error ~ |u''| h^2/8 ~ 5e-8 << 7.3e-3 tol.
//   Phase 2: per point, lerp the 16 nearest subnets from the table and do
//            the Gaussian PoU combine. Dropped subdomains have relative
//            weight < 1.4e-7 (farthest included center is 5.76 sigma away).

#define GK    7168      // grid resolution over [0,1]
#define WIDTH 2304      // samples per subdomain row (9 chunks of 256)
#define HALFW 1152

__device__ __forceinline__ int glo_of(int s) {
    // round(c_s * G) - HALFW, clamped so row indices [0, WIDTH-1] stay valid
    int g = (s * GK + 31) / 63 - HALFW;   // integer round of s*G/63
    g = g < 0 ? 0 : g;
    const int hi = GK - (WIDTH - 1);      // ensures glo + 2303 <= GK
    g = g > hi ? hi : g;
    return g;
}

__device__ __forceinline__ float tanh_fast(float v) {
    // tanh(v) = 1 - 2/(exp(2v)+1); |v| <= ~7 here so no overflow concerns.
    float e = __expf(2.0f * v);                       // v_mul + v_exp_f32
    return 1.0f - 2.0f * __builtin_amdgcn_rcpf(e + 1.0f);
}

// ---------------------------------------------------------------------------
// Phase 1: evaluate subnet s at WIDTH grid points.
// grid = 64 subdomains * 9 chunks = 576 blocks, 256 threads each.
// Weights are wave-uniform -> scalar loads; h arrays fully unrolled into
// registers (ha/hb = 128 VGPRs).
// ---------------------------------------------------------------------------
__global__ __launch_bounds__(256, 2) void eval_grid(
    const float* __restrict__ W0, const float* __restrict__ b0,
    const float* __restrict__ W1, const float* __restrict__ b1,
    const float* __restrict__ W2, const float* __restrict__ b2,
    const float* __restrict__ W3, const float* __restrict__ b3,
    float* __restrict__ U)
{
    const int s     = blockIdx.x / 9;
    const int chunk = blockIdx.x % 9;
    const int idx   = chunk * 256 + (int)threadIdx.x;   // 0..2303
    const int glo   = glo_of(s);
    const float x   = (float)(glo + idx) * (1.0f / (float)GK);

    const float* __restrict__ w0  = W0 + s * 64;
    const float* __restrict__ bb0 = b0 + s * 64;
    const float* __restrict__ w1  = W1 + s * 4096;
    const float* __restrict__ bb1 = b1 + s * 64;
    const float* __restrict__ w2  = W2 + s * 4096;
    const float* __restrict__ bb2 = b2 + s * 64;
    const float* __restrict__ w3  = W3 + s * 64;

    float ha[64];
#pragma unroll
    for (int i = 0; i < 64; ++i)
        ha[i] = tanh_fast(fmaf(w0[i], x, bb0[i]));

    float hb[64];
#pragma unroll
    for (int v = 0; v < 64; ++v) {
        float acc = bb1[v];
#pragma unroll
        for (int w = 0; w < 64; ++w)
            acc = fmaf(w1[v * 64 + w], ha[w], acc);
        hb[v] = tanh_fast(acc);
    }

#pragma unroll
    for (int v = 0; v < 64; ++v) {
        float acc = bb2[v];
#pragma unroll
        for (int w = 0; w < 64; ++w)
            acc = fmaf(w2[v * 64 + w], hb[w], acc);
        ha[v] = tanh_fast(acc);
    }

    float u = b3[s];
#pragma unroll
    for (int w = 0; w < 64; ++w)
        u = fmaf(w3[w], ha[w], u);

    U[s * WIDTH + idx] = u;
}

// ---------------------------------------------------------------------------
// Phase 2: PoU combine over the 16 nearest subdomains via table lerp.
// ---------------------------------------------------------------------------
__global__ __launch_bounds__(256) void combine(
    const float* __restrict__ x_in, const float* __restrict__ U,
    float* __restrict__ out, int N)
{
    int n = blockIdx.x * 256 + (int)threadIdx.x;
    if (n >= N) return;
    float x = x_in[n];

    int j0 = (int)floorf(x * 63.0f + 0.5f);   // nearest center index
    int lo = j0 - 8;
    lo = lo < 0 ? 0 : (lo > 48 ? 48 : lo);

    const float inv_sigma = 64.0f / 1.5f;
    const float t_all = x * (float)GK;
    float num = 0.0f, den = 0.0f;

#pragma unroll 4
    for (int k = 0; k < 16; ++k) {
        int s = lo + k;
        int glo = glo_of(s);
        float t = t_all - (float)glo;
        int it = (int)floorf(t);
        // clamp for far (negligible-weight) subdomains; in-window queries
        // always land in [0, 2302] by construction
        it = it < 0 ? 0 : (it > WIDTH - 2 ? WIDTH - 2 : it);
        float frac = t - (float)it;
        const float* __restrict__ row = U + s * WIDTH + it;
        float u0 = row[0];
        float u1 = row[1];
        float u = fmaf(frac, u1 - u0, u0);

        float d = (x - (float)s * (1.0f / 63.0f)) * inv_sigma;
        float w = __expf(-0.5f * d * d);
        num = fmaf(w, u, num);
        den += w;
    }

    out[n] = tanh_fast(5.0f * x) * num * __builtin_amdgcn_rcpf(den);
}

// ---------------------------------------------------------------------------
extern "C" void kernel_launch(void* const* d_in, const int* in_sizes, int n_in,
                              void* d_out, int out_size, void* d_ws, size_t ws_size,
                              hipStream_t stream) {
    const float* x  = (const float*)d_in[0];
    const float* W0 = (const float*)d_in[1];
    const float* b0 = (const float*)d_in[2];
    const float* W1 = (const float*)d_in[3];
    const float* b1 = (const float*)d_in[4];
    const float* W2 = (const float*)d_in[5];
    const float* b2 = (const float*)d_in[6];
    const float* W3 = (const float*)d_in[7];
    const float* b3 = (const float*)d_in[8];

    float* U   = (float*)d_ws;     // 64 * 2304 * 4 B = 576 KiB scratch
    float* out = (float*)d_out;

    eval_grid<<<dim3(576), dim3(256), 0, stream>>>(W0, b0, W1, b1, W2, b2, W3, b3, U);
    combine<<<dim3(256), dim3(256), 0, stream>>>(x, U, out, 65536);
}

// Round 2
// 143.851 us; speedup vs baseline: 1.2750x; 1.2750x over previous
//
#include <hip/hip_runtime.h>
#include <math.h>

// FBPINN PoU: S=64 subdomains, N=65536 points, W=64.
//   Phase 1: evaluate each subnet on a dense grid (G=7168), WIDTH=2304
//            samples per subdomain (lerp error ~5e-8 << 7.3e-3 tol).
//            Cooperative block: 4 waves split the 64 neurons (16 each,
//            wave-uniform v_base via readfirstlane -> scalar weight loads),
//            activations ping through LDS H[w][p] (conflict-free).
//   Phase 2: per point, lerp the 16 nearest subnets + Gaussian PoU combine
//            (dropped subdomains have relative weight < 1.4e-7).

#define GK     7168
#define WIDTH  2304
#define HALFW  1152
#define CHUNKS 36      // 36 chunks * 64 points = 2304 per subdomain

__device__ __forceinline__ int glo_of(int s) {
    int g = (s * GK + 31) / 63 - HALFW;
    g = g < 0 ? 0 : g;
    const int hi = GK - (WIDTH - 1);
    g = g > hi ? hi : g;
    return g;
}

__device__ __forceinline__ float tanh_fast(float v) {
    // tanh(v) = 1 - 2/(exp(2v)+1); |v| <= ~7 here.
    float e = __expf(2.0f * v);
    return 1.0f - 2.0f * __builtin_amdgcn_rcpf(e + 1.0f);
}

// ---------------------------------------------------------------------------
// Phase 1: block = (subdomain s, chunk of 64 grid points). 256 threads.
// lane (0..63) = point; wave (0..3) = 16-neuron slice (wave-uniform).
// Weights: block-uniform rows -> s_load_dwordx16. Activations: LDS H[w][p],
// lanes consecutive -> 2 lanes/bank (free). h[] preloaded to VGPRs per layer
// so the 16 accumulator chains are register-only and fully interleavable.
// ---------------------------------------------------------------------------
__global__ __launch_bounds__(256, 4) void eval_grid(
    const float* __restrict__ W0, const float* __restrict__ b0,
    const float* __restrict__ W1, const float* __restrict__ b1,
    const float* __restrict__ W2, const float* __restrict__ b2,
    const float* __restrict__ W3, const float* __restrict__ b3,
    float* __restrict__ U)
{
    const int s     = blockIdx.x / CHUNKS;
    const int chunk = blockIdx.x % CHUNKS;
    const int lane  = (int)threadIdx.x & 63;
    // Force wave-uniformity so all weight addresses scalarize to s_load.
    const int wv    = __builtin_amdgcn_readfirstlane((int)(threadIdx.x >> 6));
    const int vb    = wv * 16;

    const int   glo = glo_of(s);
    const int   p   = chunk * 64 + lane;            // 0..2303
    const float x   = (float)(glo + p) * (1.0f / (float)GK);

    const float* __restrict__ w0  = W0 + s * 64;
    const float* __restrict__ bb0 = b0 + s * 64;
    const float* __restrict__ w1  = W1 + s * 4096;
    const float* __restrict__ bb1 = b1 + s * 64;
    const float* __restrict__ w2  = W2 + s * 4096;
    const float* __restrict__ bb2 = b2 + s * 64;
    const float* __restrict__ w3  = W3 + s * 64;

    __shared__ float H[64][64];                     // H[neuron][point], 16 KiB

    // ---- layer 0: H0[v][p] = tanh(w0[v]*x_p + b0[v])
#pragma unroll
    for (int j = 0; j < 16; ++j) {
        int v = vb + j;
        H[v][lane] = tanh_fast(fmaf(w0[v], x, bb0[v]));
    }
    __syncthreads();

    float h[64];
    float acc[16];

    // ---- layer 1
#pragma unroll
    for (int w = 0; w < 64; ++w) h[w] = H[w][lane];
#pragma unroll
    for (int j = 0; j < 16; ++j) {
        const float* __restrict__ row = w1 + (vb + j) * 64;  // uniform -> s_load
        float a = bb1[vb + j];
#pragma unroll
        for (int w = 0; w < 64; ++w) a = fmaf(row[w], h[w], a);
        acc[j] = tanh_fast(a);
    }
    __syncthreads();
#pragma unroll
    for (int j = 0; j < 16; ++j) H[vb + j][lane] = acc[j];
    __syncthreads();

    // ---- layer 2
#pragma unroll
    for (int w = 0; w < 64; ++w) h[w] = H[w][lane];
#pragma unroll
    for (int j = 0; j < 16; ++j) {
        const float* __restrict__ row = w2 + (vb + j) * 64;
        float a = bb2[vb + j];
#pragma unroll
        for (int w = 0; w < 64; ++w) a = fmaf(row[w], h[w], a);
        acc[j] = tanh_fast(a);
    }
    __syncthreads();
#pragma unroll
    for (int j = 0; j < 16; ++j) H[vb + j][lane] = acc[j];
    __syncthreads();

    // ---- layer 3 (wave 0 only): u[p] = b3 + sum_w w3[w]*H2[w][p]
    if (wv == 0) {
        float u = b3[s];
#pragma unroll
        for (int w = 0; w < 64; ++w) u = fmaf(w3[w], H[w][lane], u);
        U[s * WIDTH + p] = u;
    }
}

// ---------------------------------------------------------------------------
// Phase 2: PoU combine over the 16 nearest subdomains via table lerp.
// Fully unrolled so all 32 L2-resident gathers issue before first use.
// ---------------------------------------------------------------------------
__global__ __launch_bounds__(256) void combine(
    const float* __restrict__ x_in, const float* __restrict__ U,
    float* __restrict__ out, int N)
{
    int n = blockIdx.x * 256 + (int)threadIdx.x;
    if (n >= N) return;
    float x = x_in[n];

    int j0 = (int)floorf(x * 63.0f + 0.5f);
    int lo = j0 - 8;
    lo = lo < 0 ? 0 : (lo > 48 ? 48 : lo);

    const float inv_sigma = 64.0f / 1.5f;
    const float t_all = x * (float)GK;

    float u0v[16], u1v[16], fracv[16], wv[16];
#pragma unroll
    for (int k = 0; k < 16; ++k) {
        int s = lo + k;
        int glo = glo_of(s);
        float t = t_all - (float)glo;
        int it = (int)floorf(t);
        it = it < 0 ? 0 : (it > WIDTH - 2 ? WIDTH - 2 : it);
        fracv[k] = t - (float)it;
        const float* __restrict__ row = U + s * WIDTH + it;
        u0v[k] = row[0];
        u1v[k] = row[1];
        float d = (x - (float)s * (1.0f / 63.0f)) * inv_sigma;
        wv[k] = __expf(-0.5f * d * d);
    }

    float num = 0.0f, den = 0.0f;
#pragma unroll
    for (int k = 0; k < 16; ++k) {
        float u = fmaf(fracv[k], u1v[k] - u0v[k], u0v[k]);
        num = fmaf(wv[k], u, num);
        den += wv[k];
    }

    out[n] = tanh_fast(5.0f * x) * num * __builtin_amdgcn_rcpf(den);
}

// ---------------------------------------------------------------------------
extern "C" void kernel_launch(void* const* d_in, const int* in_sizes, int n_in,
                              void* d_out, int out_size, void* d_ws, size_t ws_size,
                              hipStream_t stream) {
    const float* x  = (const float*)d_in[0];
    const float* W0 = (const float*)d_in[1];
    const float* b0 = (const float*)d_in[2];
    const float* W1 = (const float*)d_in[3];
    const float* b1 = (const float*)d_in[4];
    const float* W2 = (const float*)d_in[5];
    const float* b2 = (const float*)d_in[6];
    const float* W3 = (const float*)d_in[7];
    const float* b3 = (const float*)d_in[8];

    float* U   = (float*)d_ws;     // 64 * 2304 * 4 B = 576 KiB scratch
    float* out = (float*)d_out;

    eval_grid<<<dim3(64 * CHUNKS), dim3(256), 0, stream>>>(
        W0, b0, W1, b1, W2, b2, W3, b3, U);
    combine<<<dim3(256), dim3(256), 0, stream>>>(x, U, out, 65536);
}

// Round 3
// 112.935 us; speedup vs baseline: 1.6240x; 1.2738x over previous
//
#include <hip/hip_runtime.h>
#include <math.h>

// FBPINN PoU: S=64 subdomains, N=65536 points, W=64.
//   Phase 1: evaluate each subnet on a dense grid (G=7168), WIDTH=1536
//            samples per subdomain (lerp error ~5e-8 << 7.3e-3 tol).
//            Cooperative block: 4 waves split the 64 neurons (16 each,
//            wave-uniform via readfirstlane -> scalar weight loads).
//            Dot products chunked by 16 so hc[16]+acc[16] stay in VGPRs
//            (round-2's VGPR=44 showed h[64] was rematerialized from LDS:
//            1024 ds_read/layer; chunking makes it 64 ds_read/layer).
//   Phase 2: per point, lerp the 12 nearest subnets + Gaussian PoU combine.
//            Nearest dropped center is >= 4.06 sigma -> relative dropped
//            weight ~7e-5 -> output error ~3e-5.

#define GK     7168
#define WIDTH  1536
#define HALFW  768
#define CHUNKS 24      // 24 chunks * 64 points = 1536 per subdomain

__device__ __forceinline__ int glo_of(int s) {
    int g = (s * GK + 31) / 63 - HALFW;
    g = g < 0 ? 0 : g;
    const int hi = GK - (WIDTH - 1);
    g = g > hi ? hi : g;
    return g;
}

__device__ __forceinline__ float tanh_fast(float v) {
    // tanh(v) = 1 - 2/(exp(2v)+1); |v| <= ~7 here.
    float e = __expf(2.0f * v);
    return 1.0f - 2.0f * __builtin_amdgcn_rcpf(e + 1.0f);
}

// ---------------------------------------------------------------------------
// Phase 1: block = (subdomain s, chunk of 64 grid points). 256 threads.
// lane (0..63) = point; wave (0..3) = 16-neuron slice (wave-uniform).
// Weights: block-uniform rows -> s_load. Activations: LDS H[w][p], lanes
// consecutive -> 2 lanes/bank (free). Register chunking: per 16-wide w-chunk,
// hc[16] is loaded once and feeds 16x16 FMAs into 16 independent acc chains.
// ---------------------------------------------------------------------------
__global__ __launch_bounds__(256, 6) void eval_grid(
    const float* __restrict__ W0, const float* __restrict__ b0,
    const float* __restrict__ W1, const float* __restrict__ b1,
    const float* __restrict__ W2, const float* __restrict__ b2,
    const float* __restrict__ W3, const float* __restrict__ b3,
    float* __restrict__ U)
{
    const int s     = blockIdx.x / CHUNKS;
    const int chunk = blockIdx.x % CHUNKS;
    const int lane  = (int)threadIdx.x & 63;
    const int wv    = __builtin_amdgcn_readfirstlane((int)(threadIdx.x >> 6));
    const int vb    = wv * 16;

    const int   glo = glo_of(s);
    const int   p   = chunk * 64 + lane;            // 0..1535
    const float x   = (float)(glo + p) * (1.0f / (float)GK);

    const float* __restrict__ w0  = W0 + s * 64;
    const float* __restrict__ bb0 = b0 + s * 64;
    const float* __restrict__ w1  = W1 + s * 4096;
    const float* __restrict__ bb1 = b1 + s * 64;
    const float* __restrict__ w2  = W2 + s * 4096;
    const float* __restrict__ bb2 = b2 + s * 64;
    const float* __restrict__ w3  = W3 + s * 64;

    __shared__ float H[64][64];                     // H[neuron][point], 16 KiB

    // ---- layer 0
#pragma unroll
    for (int j = 0; j < 16; ++j) {
        int v = vb + j;
        H[v][lane] = tanh_fast(fmaf(w0[v], x, bb0[v]));
    }
    __syncthreads();

    float acc[16];

    // ---- layer 1
#pragma unroll
    for (int j = 0; j < 16; ++j) acc[j] = bb1[vb + j];
#pragma unroll
    for (int wb = 0; wb < 4; ++wb) {
        float hc[16];
#pragma unroll
        for (int i = 0; i < 16; ++i) hc[i] = H[wb * 16 + i][lane];
#pragma unroll
        for (int j = 0; j < 16; ++j) {
            const float* __restrict__ rw = w1 + (vb + j) * 64 + wb * 16;
#pragma unroll
            for (int i = 0; i < 16; ++i) acc[j] = fmaf(rw[i], hc[i], acc[j]);
        }
    }
    __syncthreads();                                // all reads of H0 done
#pragma unroll
    for (int j = 0; j < 16; ++j) H[vb + j][lane] = tanh_fast(acc[j]);
    __syncthreads();

    // ---- layer 2
#pragma unroll
    for (int j = 0; j < 16; ++j) acc[j] = bb2[vb + j];
#pragma unroll
    for (int wb = 0; wb < 4; ++wb) {
        float hc[16];
#pragma unroll
        for (int i = 0; i < 16; ++i) hc[i] = H[wb * 16 + i][lane];
#pragma unroll
        for (int j = 0; j < 16; ++j) {
            const float* __restrict__ rw = w2 + (vb + j) * 64 + wb * 16;
#pragma unroll
            for (int i = 0; i < 16; ++i) acc[j] = fmaf(rw[i], hc[i], acc[j]);
        }
    }
    __syncthreads();                                // all reads of H1 done
#pragma unroll
    for (int j = 0; j < 16; ++j) H[vb + j][lane] = tanh_fast(acc[j]);
    __syncthreads();

    // ---- layer 3 (wave 0 only)
    if (wv == 0) {
        float u = b3[s];
#pragma unroll
        for (int w = 0; w < 64; ++w) u = fmaf(w3[w], H[w][lane], u);
        U[s * WIDTH + p] = u;
    }
}

// ---------------------------------------------------------------------------
// Phase 2: PoU combine over the 12 nearest subdomains via table lerp.
// ---------------------------------------------------------------------------
__global__ __launch_bounds__(256) void combine(
    const float* __restrict__ x_in, const float* __restrict__ U,
    float* __restrict__ out, int N)
{
    int n = blockIdx.x * 256 + (int)threadIdx.x;
    if (n >= N) return;
    float x = x_in[n];

    int jf = (int)floorf(x * 63.0f);    // floor center index
    int lo = jf - 5;                    // window jf-5 .. jf+6 (12 subnets)
    lo = lo < 0 ? 0 : (lo > 52 ? 52 : lo);

    const float inv_sigma = 64.0f / 1.5f;
    const float t_all = x * (float)GK;

    float u0v[12], u1v[12], fracv[12], wv[12];
#pragma unroll
    for (int k = 0; k < 12; ++k) {
        int s = lo + k;
        int glo = glo_of(s);
        float t = t_all - (float)glo;
        int it = (int)floorf(t);
        it = it < 0 ? 0 : (it > WIDTH - 2 ? WIDTH - 2 : it);
        fracv[k] = t - (float)it;
        const float* __restrict__ row = U + s * WIDTH + it;
        u0v[k] = row[0];
        u1v[k] = row[1];
        float d = (x - (float)s * (1.0f / 63.0f)) * inv_sigma;
        wv[k] = __expf(-0.5f * d * d);
    }

    float num = 0.0f, den = 0.0f;
#pragma unroll
    for (int k = 0; k < 12; ++k) {
        float u = fmaf(fracv[k], u1v[k] - u0v[k], u0v[k]);
        num = fmaf(wv[k], u, num);
        den += wv[k];
    }

    out[n] = tanh_fast(5.0f * x) * num * __builtin_amdgcn_rcpf(den);
}

// ---------------------------------------------------------------------------
extern "C" void kernel_launch(void* const* d_in, const int* in_sizes, int n_in,
                              void* d_out, int out_size, void* d_ws, size_t ws_size,
                              hipStream_t stream) {
    const float* x  = (const float*)d_in[0];
    const float* W0 = (const float*)d_in[1];
    const float* b0 = (const float*)d_in[2];
    const float* W1 = (const float*)d_in[3];
    const float* b1 = (const float*)d_in[4];
    const float* W2 = (const float*)d_in[5];
    const float* b2 = (const float*)d_in[6];
    const float* W3 = (const float*)d_in[7];
    const float* b3 = (const float*)d_in[8];

    float* U   = (float*)d_ws;     // 64 * 1536 * 4 B = 384 KiB scratch
    float* out = (float*)d_out;

    eval_grid<<<dim3(64 * CHUNKS), dim3(256), 0, stream>>>(
        W0, b0, W1, b1, W2, b2, W3, b3, U);
    combine<<<dim3(256), dim3(256), 0, stream>>>(x, U, out, 65536);
}